// Round 14
// baseline (64.222 us; speedup 1.0000x reference)
//
#include <hip/hip_runtime.h>
#include <hip/hip_bf16.h>

// Fused GNN layer, restructured via linearity:
//   relu((x + mean_src(x))W + b) = relu(z + mean_src(z) + b),  z = x@W
//
// T0 (ws >= ~26 MB):
//   K1 gemm_z: rp scatter + z = bf16(x@W) coalesced to ws (+ zero row at z[N])
//              x read via NONTEMPORAL loads (read-once; keep L3 for z)
//   K2 agg: quarter-wave per row, bf16 gathers of z[src] (cached, L3-resident),
//           + z[self] + bias, relu, NONTEMPORAL fp32 store (no RFO, no L3 pollution).
// T2: self-contained single kernel (binary search + inline W pack).

#define FD  128
#define BR  64
#define HSB 136    // LDS row stride in bf16 elems (K1 tile)

typedef __attribute__((ext_vector_type(8))) short bf16x8;
typedef __attribute__((ext_vector_type(4))) float f32x4;

__device__ __forceinline__ short f2bf(float f) {
    unsigned u = __float_as_uint(f);
    return (short)((u + 0x7FFFu + ((u >> 16) & 1u)) >> 16);   // RNE
}
__device__ __forceinline__ float bf2f(short s) {
    return __uint_as_float(((unsigned)(unsigned short)s) << 16);
}

// ---------------- K1: rp scatter + z = bf16(x@W) ----------------
__global__ __launch_bounds__(256) void gemm_z_kernel(
    const float* __restrict__ x, const float* __restrict__ W,
    const int* __restrict__ edst, int* __restrict__ rp,
    short* __restrict__ zb, int N, int E)
{
    __shared__ short sh[BR * HSB];   // 17408 B
    const int t = threadIdx.x;
    const int base = blockIdx.x * BR;

    // rp scatter (edge_dst sorted), grid-stride
    for (int e = blockIdx.x * 256 + t; e < E; e += gridDim.x * 256) {
        int cur = edst[e];
        int prev = e ? edst[e - 1] : -1;
        for (int v = prev + 1; v <= cur; ++v) rp[v] = e;
        if (e == E - 1)
            for (int v = cur + 1; v <= N; ++v) rp[v] = E;
    }
    if (E == 0)
        for (int v = blockIdx.x * 256 + t; v <= N; v += gridDim.x * 256) rp[v] = 0;
    if (blockIdx.x == 0 && t < 16) {   // zero row at zb[N]
        bf16x8 z = {0, 0, 0, 0, 0, 0, 0, 0};
        *(bf16x8*)(zb + (size_t)N * FD + t * 8) = z;
    }

    // stage x tile (64x128 fp32) -> bf16 LDS, coalesced, NONTEMPORAL reads
#pragma unroll
    for (int i = 0; i < 8; ++i) {
        int off = i * 1024 + t * 4;           // element offset in tile
        int row = off >> 7, col = off & 127;
        int gr = base + row;
        f32x4 v = (f32x4){0.f, 0.f, 0.f, 0.f};
        if (gr < N)
            v = __builtin_nontemporal_load((const f32x4*)(x + (size_t)gr * FD + col));
        short4 s4;
        s4.x = f2bf(v.x); s4.y = f2bf(v.y); s4.z = f2bf(v.z); s4.w = f2bf(v.w);
        *(short4*)(sh + row * HSB + col) = s4;
    }
    __syncthreads();

    // GEMM: wave owns 32 cols; W fragments assembled inline (L2-hot)
    const int wave = t >> 6, lane = t & 63;
    const int lr = lane & 15, q = lane >> 4;
    const int colb = wave * 32;

    bf16x8 bfr[2][4];
#pragma unroll
    for (int ct = 0; ct < 2; ++ct) {
        int col = colb + ct * 16 + lr;
#pragma unroll
        for (int kt = 0; kt < 4; ++kt) {
            bf16x8 f;
#pragma unroll
            for (int e = 0; e < 8; ++e)
                f[e] = f2bf(W[(size_t)(kt * 32 + q * 8 + e) * FD + col]);
            bfr[ct][kt] = f;
        }
    }

    f32x4 acc[4][2];
#pragma unroll
    for (int rt = 0; rt < 4; ++rt) {
        acc[rt][0] = (f32x4){0.f, 0.f, 0.f, 0.f};
        acc[rt][1] = (f32x4){0.f, 0.f, 0.f, 0.f};
    }
#pragma unroll
    for (int rt = 0; rt < 4; ++rt)
#pragma unroll
        for (int kt = 0; kt < 4; ++kt) {
            bf16x8 av = *(const bf16x8*)(sh + (rt * 16 + lr) * HSB + kt * 32 + q * 8);
            acc[rt][0] = __builtin_amdgcn_mfma_f32_16x16x32_bf16(av, bfr[0][kt], acc[rt][0], 0, 0, 0);
            acc[rt][1] = __builtin_amdgcn_mfma_f32_16x16x32_bf16(av, bfr[1][kt], acc[rt][1], 0, 0, 0);
        }

    __syncthreads();   // all A-reads done before overwriting sh with C

    // C -> bf16 into sh (C layout: col = colb+ct*16+lr, row = rt*16 + q*4 + j)
#pragma unroll
    for (int rt = 0; rt < 4; ++rt)
#pragma unroll
        for (int ct = 0; ct < 2; ++ct)
#pragma unroll
            for (int j = 0; j < 4; ++j)
                sh[(rt * 16 + q * 4 + j) * HSB + colb + ct * 16 + lr] = f2bf(acc[rt][ct][j]);
    __syncthreads();

    // coalesced bf16 store of z tile (cached — z must stay L3-resident for K2)
#pragma unroll
    for (int i = 0; i < 4; ++i) {
        int off = i * 2048 + t * 8;
        int row = off >> 7, col = off & 127;
        int gr = base + row;
        if (gr < N)
            *(bf16x8*)(zb + (size_t)gr * FD + col) = *(const bf16x8*)(sh + row * HSB + col);
    }
}

// ---------------- K2: gather-mean epilogue (no GEMM, nt stores) ----------------
__global__ __launch_bounds__(256) void agg_kernel(
    const short* __restrict__ zb, const float* __restrict__ bias,
    const int* __restrict__ esrc, const int* __restrict__ rp,
    float* __restrict__ out, int N, int E)
{
    __shared__ int seg[BR + 1];
    const int t = threadIdx.x;
    const int base = blockIdx.x * BR;

    if (t < BR + 1) {
        int idx = base + t;
        seg[t] = rp[idx > N ? N : idx];
    }
    __syncthreads();

    const int wave = t >> 6, lane = t & 63;
    const int qw = lane >> 4, ql = lane & 15, qb = qw << 4;
    const int rowbase = wave * 16;

    // bias for my 8 columns (L1-hot)
    const float4 bja = *(const float4*)(bias + 8 * ql);
    const float4 bjb = *(const float4*)(bias + 8 * ql + 4);

    // prologue: prefetch it=0
    int rb0 = rowbase + qw;
    int r0  = base + rb0;
    int s = (r0 < N) ? seg[rb0] : 0;
    int e = (r0 < N) ? seg[rb0 + 1] : 0;
    int srcv_n = (s + ql < e) ? esrc[s + ql] : 0;
    bf16x8 zv_n = {0, 0, 0, 0, 0, 0, 0, 0};
    if (r0 < N) zv_n = *(const bf16x8*)(zb + (size_t)r0 * FD + 8 * ql);

    for (int it = 0; it < 4; ++it) {
        const int cur_rb = rowbase + it * 4 + qw;
        const int cur_r  = base + cur_rb;
        const int cs0 = s, ce = e;
        int srcv = srcv_n;
        const bf16x8 zv = zv_n;

        // prefetch next iteration (indices + self row)
        if (it < 3) {
            int nrb = rowbase + (it + 1) * 4 + qw;
            int nr  = base + nrb;
            s = (nr < N) ? seg[nrb] : 0;
            e = (nr < N) ? seg[nrb + 1] : 0;
            srcv_n = (s + ql < e) ? esrc[s + ql] : 0;
            bf16x8 z = {0, 0, 0, 0, 0, 0, 0, 0};
            zv_n = z;
            if (nr < N) zv_n = *(const bf16x8*)(zb + (size_t)nr * FD + 8 * ql);
        }

        if (cur_r < N) {
            float av[8];
#pragma unroll
            for (int p = 0; p < 8; ++p) av[p] = 0.f;

            for (int cs = cs0; cs < ce; cs += 16) {
                int m = ce - cs; if (m > 16) m = 16;
                if (cs != cs0)   // deg > 16: reload index batch
                    srcv = (cs + ql < ce) ? esrc[cs + ql] : 0;
                for (int j0 = 0; j0 < m; j0 += 8) {
                    uint4 v[8];
#pragma unroll
                    for (int u = 0; u < 8; ++u) {
                        int jj = j0 + u;
                        int idx = __shfl(srcv, qb + (jj & 15));
                        if (jj >= m) idx = N;   // dummy -> zero row
                        v[u] = *(const uint4*)(zb + (size_t)idx * FD + 8 * ql);
                    }
#pragma unroll
                    for (int u = 0; u < 8; ++u) {
                        unsigned w;
                        w = v[u].x;
                        av[0] += __uint_as_float(w << 16);
                        av[1] += __uint_as_float(w & 0xFFFF0000u);
                        w = v[u].y;
                        av[2] += __uint_as_float(w << 16);
                        av[3] += __uint_as_float(w & 0xFFFF0000u);
                        w = v[u].z;
                        av[4] += __uint_as_float(w << 16);
                        av[5] += __uint_as_float(w & 0xFFFF0000u);
                        w = v[u].w;
                        av[6] += __uint_as_float(w << 16);
                        av[7] += __uint_as_float(w & 0xFFFF0000u);
                    }
                }
            }
            int deg = ce - cs0;
            float inv = 1.0f / (float)(deg > 0 ? deg : 1);
            float o[8];
            o[0] = bf2f(zv[0]) + av[0] * inv + bja.x;
            o[1] = bf2f(zv[1]) + av[1] * inv + bja.y;
            o[2] = bf2f(zv[2]) + av[2] * inv + bja.z;
            o[3] = bf2f(zv[3]) + av[3] * inv + bja.w;
            o[4] = bf2f(zv[4]) + av[4] * inv + bjb.x;
            o[5] = bf2f(zv[5]) + av[5] * inv + bjb.y;
            o[6] = bf2f(zv[6]) + av[6] * inv + bjb.z;
            o[7] = bf2f(zv[7]) + av[7] * inv + bjb.w;
#pragma unroll
            for (int p = 0; p < 8; ++p) o[p] = o[p] > 0.f ? o[p] : 0.f;
            // NONTEMPORAL stores (native ext-vector type): no RFO, no L3 pollution
            f32x4 oa = (f32x4){o[0], o[1], o[2], o[3]};
            f32x4 ob = (f32x4){o[4], o[5], o[6], o[7]};
            __builtin_nontemporal_store(oa, (f32x4*)(out + (size_t)cur_r * FD + 8 * ql));
            __builtin_nontemporal_store(ob, (f32x4*)(out + (size_t)cur_r * FD + 8 * ql + 4));
        }
    }
}

// ---------------- T2: self-contained fallback ----------------
__global__ __launch_bounds__(256) void meanagg_fused_kernel(
    const float* __restrict__ x, const float* __restrict__ W,
    const float* __restrict__ bias, const int* __restrict__ esrc,
    const int* __restrict__ edst, float* __restrict__ out, int N, int E)
{
    __shared__ short shb[BR * HSB];
    __shared__ int seg[BR + 1];

    const int t = threadIdx.x;
    const int base = blockIdx.x * BR;

    if (t < BR + 1) {
        int v = base + t;
        int lo = 0, hi = E;
        while (lo < hi) {
            int mid = (lo + hi) >> 1;
            if (edst[mid] < v) lo = mid + 1; else hi = mid;
        }
        seg[t] = lo;
    }
    __syncthreads();

    const int wave = t >> 6;
    const int lane = t & 63;
    const int sw = lane >> 5;
    const int sl = lane & 31;
    const int lb = sw << 5;
    const int rowbase = wave * 16;

    for (int it = 0; it < 8; ++it) {
        int cur_rb = rowbase + it * 2 + sw;
        int cur_r  = base + cur_rb;
        if (cur_r >= N) break;
        int cur_s = seg[cur_rb], cur_e = seg[cur_rb + 1];
        float4 a0 = make_float4(0.f, 0.f, 0.f, 0.f), a1 = a0;
        for (int cs = cur_s; cs < cur_e; cs += 32) {
            int m = cur_e - cs; if (m > 32) m = 32;
            int srcv = (cs + sl < cur_e) ? esrc[cs + sl] : 0;
            for (int j0 = 0; j0 < m; j0 += 8) {
                const int rem = m - j0;
#pragma unroll
                for (int u = 0; u < 8; ++u) {
                    int idx = __shfl(srcv, lb + ((j0 + u) & 31));
                    float4 v = *(const float4*)(x + (size_t)idx * FD + 4 * sl);
                    float f = (u < rem) ? 1.f : 0.f;
                    float4* A = (u & 1) ? &a1 : &a0;
                    A->x = fmaf(v.x, f, A->x);
                    A->y = fmaf(v.y, f, A->y);
                    A->z = fmaf(v.z, f, A->z);
                    A->w = fmaf(v.w, f, A->w);
                }
            }
        }
        float4 xvv = *(const float4*)(x + (size_t)cur_r * FD + 4 * sl);
        int deg = cur_e - cur_s;
        float inv = 1.0f / (float)(deg > 0 ? deg : 1);
        short4 hb;
        hb.x = f2bf(xvv.x + (a0.x + a1.x) * inv);
        hb.y = f2bf(xvv.y + (a0.y + a1.y) * inv);
        hb.z = f2bf(xvv.z + (a0.z + a1.z) * inv);
        hb.w = f2bf(xvv.w + (a0.w + a1.w) * inv);
        *(short4*)(shb + cur_rb * HSB + 4 * sl) = hb;
    }
    __syncthreads();

    const int lr = lane & 15;
    const int q  = lane >> 4;
    const int colb = wave * 32;

    bf16x8 bfr[2][4];
#pragma unroll
    for (int ct = 0; ct < 2; ++ct) {
        int col = colb + ct * 16 + lr;
#pragma unroll
        for (int kt = 0; kt < 4; ++kt) {
            bf16x8 f;
#pragma unroll
            for (int e = 0; e < 8; ++e)
                f[e] = f2bf(W[(size_t)(kt * 32 + q * 8 + e) * FD + col]);
            bfr[ct][kt] = f;
        }
    }

    f32x4 acc[4][2];
#pragma unroll
    for (int rt = 0; rt < 4; ++rt) {
        acc[rt][0] = (f32x4){0.f, 0.f, 0.f, 0.f};
        acc[rt][1] = (f32x4){0.f, 0.f, 0.f, 0.f};
    }
#pragma unroll
    for (int rt = 0; rt < 4; ++rt)
#pragma unroll
        for (int kt = 0; kt < 4; ++kt) {
            bf16x8 av = *(const bf16x8*)(shb + (rt * 16 + lr) * HSB + kt * 32 + q * 8);
            acc[rt][0] = __builtin_amdgcn_mfma_f32_16x16x32_bf16(av, bfr[0][kt], acc[rt][0], 0, 0, 0);
            acc[rt][1] = __builtin_amdgcn_mfma_f32_16x16x32_bf16(av, bfr[1][kt], acc[rt][1], 0, 0, 0);
        }

    const float b0 = bias[colb + lr];
    const float b1 = bias[colb + 16 + lr];

#pragma unroll
    for (int rt = 0; rt < 4; ++rt)
#pragma unroll
        for (int j = 0; j < 4; ++j) {
            int row = base + rt * 16 + q * 4 + j;
            if (row < N) {
                float v0 = acc[rt][0][j] + b0; v0 = v0 > 0.f ? v0 : 0.f;
                float v1 = acc[rt][1][j] + b1; v1 = v1 > 0.f ? v1 : 0.f;
                out[(size_t)row * FD + colb + lr]      = v0;
                out[(size_t)row * FD + colb + 16 + lr] = v1;
            }
        }
}

extern "C" void kernel_launch(void* const* d_in, const int* in_sizes, int n_in,
                              void* d_out, int out_size, void* d_ws, size_t ws_size,
                              hipStream_t stream) {
    const float* x    = (const float*)d_in[0];
    const float* W    = (const float*)d_in[1];
    const float* bias = (const float*)d_in[2];
    const int* esrc   = (const int*)d_in[3];
    const int* edst   = (const int*)d_in[4];
    float* out        = (float*)d_out;

    int N = in_sizes[0] / FD;
    int E = in_sizes[3];
    int blocks = (N + BR - 1) / BR;

    size_t rp_bytes = (size_t)(N + 1) * 4;
    size_t zb_off   = (rp_bytes + 511) & ~(size_t)511;
    size_t need     = zb_off + (size_t)(N + 1) * FD * 2;   // rp + zb (+ zero row)

    if (ws_size >= need) {
        int* rp   = (int*)d_ws;
        short* zb = (short*)((char*)d_ws + zb_off);
        gemm_z_kernel<<<blocks, 256, 0, stream>>>(x, W, edst, rp, zb, N, E);
        agg_kernel<<<blocks, 256, 0, stream>>>(zb, bias, esrc, rp, out, N, E);
    } else {
        meanagg_fused_kernel<<<blocks, 256, 0, stream>>>(x, W, bias, esrc, edst, out, N, E);
    }
}

// Round 15
// 57.731 us; speedup vs baseline: 1.1124x; 1.1124x over previous
//
#include <hip/hip_runtime.h>
#include <hip/hip_bf16.h>

// Fused GNN layer: h = x + segment_mean(x[edge_src] by edge_dst); out = relu(h@W + b)
//
// Full path (ws >= ~26.5 MB):
//   prep_full: row_ptr scatter + W bf16 MFMA-fragment pack + x -> bf16 (xb)
//   main2: BR=64/block; quarter-wave (16 lanes) per row => 4 rows in flight
//          per wave, bf16 gathers (256 B/row), 6-deep predicated batches;
//          bf16 MFMA 16x16x32 GEMM with packed W.
// Medium path (ws >= ~433 KB): fp32 gather, rp + pkW.
// Small path: self-contained kernel (binary search + inline W pack).
//
// MEASURED BEST (round 8): 57.6 us total, absmax 0.03125.

#define FD  128
#define BR  64
#define HSB 136    // LDS h row stride in bf16 elems

typedef __attribute__((ext_vector_type(8))) short bf16x8;
typedef __attribute__((ext_vector_type(4))) float f32x4;

__device__ __forceinline__ short f2bf(float f) {
    unsigned u = __float_as_uint(f);
    return (short)((u + 0x7FFFu + ((u >> 16) & 1u)) >> 16);   // RNE
}
__device__ __forceinline__ float bf2f(short s) {
    return __uint_as_float(((unsigned)(unsigned short)s) << 16);
}

// ---------------- prep (full): rp + packed W + x->bf16 ----------------
__global__ __launch_bounds__(256) void prep_full_kernel(
    const float* __restrict__ x, const float* __restrict__ W,
    const int* __restrict__ edst, int* __restrict__ rp,
    short* __restrict__ pkW, short* __restrict__ xb, int N, int E)
{
    const int gid = blockIdx.x * 256 + threadIdx.x;
    const int nth = gridDim.x * 256;

    // x -> bf16, 8 elems/thread, grid-stride
    const int nv = N * FD / 8;
    for (int i = gid; i < nv; i += nth) {
        float4 f0 = *(const float4*)(x + (size_t)i * 8);
        float4 f1 = *(const float4*)(x + (size_t)i * 8 + 4);
        short tmp[8] = {f2bf(f0.x), f2bf(f0.y), f2bf(f0.z), f2bf(f0.w),
                        f2bf(f1.x), f2bf(f1.y), f2bf(f1.z), f2bf(f1.w)};
        *(bf16x8*)(xb + (size_t)i * 8) = *(bf16x8*)tmp;
    }
    // row_ptr scatter (edge_dst sorted)
    for (int e = gid; e < E; e += nth) {
        int cur = edst[e];
        int prev = e ? edst[e - 1] : -1;
        for (int v = prev + 1; v <= cur; ++v) rp[v] = e;
        if (e == E - 1)
            for (int v = cur + 1; v <= N; ++v) rp[v] = E;
    }
    if (E == 0) {
        for (int v = gid; v <= N; v += nth) rp[v] = 0;
    }
    // W pack: f = wave*512 + ct*256 + kt*64 + lane; lane = q*16+lr
    if (gid < 2048) {
        int wave = gid >> 9, rem = gid & 511;
        int ct = rem >> 8, rem2 = rem & 255;
        int kt = rem2 >> 6, lane = rem2 & 63;
        int q = lane >> 4, lr = lane & 15;
        int col = wave * 32 + ct * 16 + lr;
        int k0 = kt * 32 + q * 8;
        short tmp[8];
#pragma unroll
        for (int e2 = 0; e2 < 8; ++e2)
            tmp[e2] = f2bf(W[(size_t)(k0 + e2) * FD + col]);
        *(bf16x8*)(pkW + (size_t)gid * 8) = *(bf16x8*)tmp;
    }
}

// ---------------- main2: bf16 gather, quarter-wave per row ----------------
__global__ __launch_bounds__(256) void meanagg_main2_kernel(
    const short* __restrict__ xb, const short* __restrict__ pkW,
    const float* __restrict__ bias, const int* __restrict__ esrc,
    const int* __restrict__ rp, float* __restrict__ out, int N, int E)
{
    __shared__ short shb[BR * HSB];
    __shared__ int seg[BR + 1];

    const int t = threadIdx.x;
    const int base = blockIdx.x * BR;

    if (t < BR + 1) {
        int idx = base + t;
        seg[t] = rp[idx > N ? N : idx];
    }
    __syncthreads();

    const int wave = t >> 6;
    const int lane = t & 63;
    const int qw = lane >> 4;      // quarter-wave: row within group of 4
    const int ql = lane & 15;      // sublane: owns features [8ql, 8ql+8)
    const int qb = qw << 4;        // shfl lane base
    const int rowbase = wave * 16;

    {
        // prologue: prefetch it=0
        int rb0 = rowbase + qw;
        int r0  = base + rb0;
        int s = (r0 < N) ? seg[rb0] : 0;
        int e = (r0 < N) ? seg[rb0 + 1] : 0;
        int srcv_n = (s + ql < e) ? esrc[s + ql] : 0;
        bf16x8 xv_n = {0, 0, 0, 0, 0, 0, 0, 0};
        if (r0 < N) xv_n = *(const bf16x8*)(xb + (size_t)r0 * FD + 8 * ql);

        for (int it = 0; it < 4; ++it) {
            const int cur_rb = rowbase + it * 4 + qw;
            const int cur_r  = base + cur_rb;
            const int cs0 = s, ce = e;
            int srcv = srcv_n;
            const bf16x8 xv = xv_n;

            // prefetch next iteration (indices + self row)
            if (it < 3) {
                int nrb = rowbase + (it + 1) * 4 + qw;
                int nr  = base + nrb;
                s = (nr < N) ? seg[nrb] : 0;
                e = (nr < N) ? seg[nrb + 1] : 0;
                srcv_n = (s + ql < e) ? esrc[s + ql] : 0;
                bf16x8 z = {0, 0, 0, 0, 0, 0, 0, 0};
                xv_n = z;
                if (nr < N) xv_n = *(const bf16x8*)(xb + (size_t)nr * FD + 8 * ql);
            }

            if (cur_r < N) {
                float a[8];
#pragma unroll
                for (int p = 0; p < 8; ++p) a[p] = 0.f;

                for (int cs = cs0; cs < ce; cs += 16) {
                    int m = ce - cs; if (m > 16) m = 16;
                    if (cs != cs0)   // deg > 16: reload index batch
                        srcv = (cs + ql < ce) ? esrc[cs + ql] : 0;
                    for (int j0 = 0; j0 < m; j0 += 6) {
                        uint4 v[6];
#pragma unroll
                        for (int u = 0; u < 6; ++u) {
                            int jj = j0 + u;
                            int idx = __shfl(srcv, qb + (jj & 15));
                            if (jj >= m) idx = 0;   // dummy -> hot row 0
                            v[u] = *(const uint4*)(xb + (size_t)idx * FD + 8 * ql);
                        }
#pragma unroll
                        for (int u = 0; u < 6; ++u) {
                            float f = (j0 + u < m) ? 1.f : 0.f;
                            unsigned w;
                            w = v[u].x;
                            a[0] = fmaf(__uint_as_float(w << 16), f, a[0]);
                            a[1] = fmaf(__uint_as_float(w & 0xFFFF0000u), f, a[1]);
                            w = v[u].y;
                            a[2] = fmaf(__uint_as_float(w << 16), f, a[2]);
                            a[3] = fmaf(__uint_as_float(w & 0xFFFF0000u), f, a[3]);
                            w = v[u].z;
                            a[4] = fmaf(__uint_as_float(w << 16), f, a[4]);
                            a[5] = fmaf(__uint_as_float(w & 0xFFFF0000u), f, a[5]);
                            w = v[u].w;
                            a[6] = fmaf(__uint_as_float(w << 16), f, a[6]);
                            a[7] = fmaf(__uint_as_float(w & 0xFFFF0000u), f, a[7]);
                        }
                    }
                }
                int deg = ce - cs0;
                float inv = 1.0f / (float)(deg > 0 ? deg : 1);
                short hb[8];
#pragma unroll
                for (int p = 0; p < 8; ++p)
                    hb[p] = f2bf(bf2f(xv[p]) + a[p] * inv);
                *(bf16x8*)(shb + cur_rb * HSB + 8 * ql) = *(bf16x8*)hb;
            }
        }
    }
    __syncthreads();

    // Phase 2: bf16 MFMA GEMM
    const int lr = lane & 15;
    const int q  = lane >> 4;
    const int colb = wave * 32;

    bf16x8 bfr[2][4];
#pragma unroll
    for (int ct = 0; ct < 2; ++ct)
#pragma unroll
        for (int kt = 0; kt < 4; ++kt) {
            int f = ((wave * 2 + ct) * 4 + kt) * 64 + lane;
            bfr[ct][kt] = *(const bf16x8*)(pkW + (size_t)f * 8);
        }

    f32x4 acc[4][2];
#pragma unroll
    for (int rt = 0; rt < 4; ++rt) {
        acc[rt][0] = (f32x4){0.f, 0.f, 0.f, 0.f};
        acc[rt][1] = (f32x4){0.f, 0.f, 0.f, 0.f};
    }

#pragma unroll
    for (int rt = 0; rt < 4; ++rt)
#pragma unroll
        for (int kt = 0; kt < 4; ++kt) {
            bf16x8 av = *(const bf16x8*)(shb + (rt * 16 + lr) * HSB + kt * 32 + q * 8);
            acc[rt][0] = __builtin_amdgcn_mfma_f32_16x16x32_bf16(av, bfr[0][kt], acc[rt][0], 0, 0, 0);
            acc[rt][1] = __builtin_amdgcn_mfma_f32_16x16x32_bf16(av, bfr[1][kt], acc[rt][1], 0, 0, 0);
        }

    const float b0 = bias[colb + lr];
    const float b1 = bias[colb + 16 + lr];

#pragma unroll
    for (int rt = 0; rt < 4; ++rt)
#pragma unroll
        for (int j = 0; j < 4; ++j) {
            int row = base + rt * 16 + q * 4 + j;
            if (row < N) {
                float v0 = acc[rt][0][j] + b0; v0 = v0 > 0.f ? v0 : 0.f;
                float v1 = acc[rt][1][j] + b1; v1 = v1 > 0.f ? v1 : 0.f;
                out[(size_t)row * FD + colb + lr]      = v0;
                out[(size_t)row * FD + colb + 16 + lr] = v1;
            }
        }
}

// ---------------- medium path: rp + pkW, fp32 gather ----------------
__global__ __launch_bounds__(256) void prep_kernel(
    const float* __restrict__ W, const int* __restrict__ edst,
    int* __restrict__ rp, short* __restrict__ pkW, int N, int E)
{
    int gid = blockIdx.x * 256 + threadIdx.x;
    if (gid < E) {
        int cur = edst[gid];
        int prev = gid ? edst[gid - 1] : -1;
        for (int v = prev + 1; v <= cur; ++v) rp[v] = gid;
        if (gid == E - 1)
            for (int v = cur + 1; v <= N; ++v) rp[v] = E;
    }
    if (gid < 2048) {
        int wave = gid >> 9, rem = gid & 511;
        int ct = rem >> 8, rem2 = rem & 255;
        int kt = rem2 >> 6, lane = rem2 & 63;
        int q = lane >> 4, lr = lane & 15;
        int col = wave * 32 + ct * 16 + lr;
        int k0 = kt * 32 + q * 8;
        short tmp[8];
#pragma unroll
        for (int e = 0; e < 8; ++e)
            tmp[e] = f2bf(W[(size_t)(k0 + e) * FD + col]);
        *(bf16x8*)(pkW + (size_t)gid * 8) = *(bf16x8*)tmp;
    }
}

__global__ __launch_bounds__(256) void meanagg_main_kernel(
    const float* __restrict__ x, const short* __restrict__ pkW,
    const float* __restrict__ bias, const int* __restrict__ esrc,
    const int* __restrict__ rp, float* __restrict__ out, int N, int E)
{
    __shared__ short shb[BR * HSB];
    __shared__ int seg[BR + 1];

    const int t = threadIdx.x;
    const int base = blockIdx.x * BR;

    if (t < BR + 1) {
        int idx = base + t;
        seg[t] = rp[idx > N ? N : idx];
    }
    __syncthreads();

    const int wave = t >> 6;
    const int lane = t & 63;
    const int sw = lane >> 5;
    const int sl = lane & 31;
    const int lb = sw << 5;
    const int rowbase = wave * 16;

    for (int it = 0; it < 8; ++it) {
        int cur_rb = rowbase + it * 2 + sw;
        int cur_r  = base + cur_rb;
        if (cur_r >= N) break;
        int cur_s = seg[cur_rb], cur_e = seg[cur_rb + 1];
        float4 a0 = make_float4(0.f, 0.f, 0.f, 0.f), a1 = a0;
        for (int cs = cur_s; cs < cur_e; cs += 32) {
            int m = cur_e - cs; if (m > 32) m = 32;
            int srcv = (cs + sl < cur_e) ? esrc[cs + sl] : 0;
            for (int j0 = 0; j0 < m; j0 += 8) {
                const int rem = m - j0;
#pragma unroll
                for (int u = 0; u < 8; ++u) {
                    int idx = __shfl(srcv, lb + ((j0 + u) & 31));
                    float4 v = *(const float4*)(x + (size_t)idx * FD + 4 * sl);
                    float f = (u < rem) ? 1.f : 0.f;
                    float4* A = (u & 1) ? &a1 : &a0;
                    A->x = fmaf(v.x, f, A->x);
                    A->y = fmaf(v.y, f, A->y);
                    A->z = fmaf(v.z, f, A->z);
                    A->w = fmaf(v.w, f, A->w);
                }
            }
        }
        float4 xvv = *(const float4*)(x + (size_t)cur_r * FD + 4 * sl);
        int deg = cur_e - cur_s;
        float inv = 1.0f / (float)(deg > 0 ? deg : 1);
        short4 hb;
        hb.x = f2bf(xvv.x + (a0.x + a1.x) * inv);
        hb.y = f2bf(xvv.y + (a0.y + a1.y) * inv);
        hb.z = f2bf(xvv.z + (a0.z + a1.z) * inv);
        hb.w = f2bf(xvv.w + (a0.w + a1.w) * inv);
        *(short4*)(shb + cur_rb * HSB + 4 * sl) = hb;
    }
    __syncthreads();

    const int lr = lane & 15;
    const int q  = lane >> 4;
    const int colb = wave * 32;

    bf16x8 bfr[2][4];
#pragma unroll
    for (int ct = 0; ct < 2; ++ct)
#pragma unroll
        for (int kt = 0; kt < 4; ++kt) {
            int f = ((wave * 2 + ct) * 4 + kt) * 64 + lane;
            bfr[ct][kt] = *(const bf16x8*)(pkW + (size_t)f * 8);
        }

    f32x4 acc[4][2];
#pragma unroll
    for (int rt = 0; rt < 4; ++rt) {
        acc[rt][0] = (f32x4){0.f, 0.f, 0.f, 0.f};
        acc[rt][1] = (f32x4){0.f, 0.f, 0.f, 0.f};
    }

#pragma unroll
    for (int rt = 0; rt < 4; ++rt)
#pragma unroll
        for (int kt = 0; kt < 4; ++kt) {
            bf16x8 av = *(const bf16x8*)(shb + (rt * 16 + lr) * HSB + kt * 32 + q * 8);
            acc[rt][0] = __builtin_amdgcn_mfma_f32_16x16x32_bf16(av, bfr[0][kt], acc[rt][0], 0, 0, 0);
            acc[rt][1] = __builtin_amdgcn_mfma_f32_16x16x32_bf16(av, bfr[1][kt], acc[rt][1], 0, 0, 0);
        }

    const float b0 = bias[colb + lr];
    const float b1 = bias[colb + 16 + lr];

#pragma unroll
    for (int rt = 0; rt < 4; ++rt)
#pragma unroll
        for (int j = 0; j < 4; ++j) {
            int row = base + rt * 16 + q * 4 + j;
            if (row < N) {
                float v0 = acc[rt][0][j] + b0; v0 = v0 > 0.f ? v0 : 0.f;
                float v1 = acc[rt][1][j] + b1; v1 = v1 > 0.f ? v1 : 0.f;
                out[(size_t)row * FD + colb + lr]      = v0;
                out[(size_t)row * FD + colb + 16 + lr] = v1;
            }
        }
}

// ---------------- small path: self-contained ----------------
__global__ __launch_bounds__(256) void meanagg_fused_kernel(
    const float* __restrict__ x, const float* __restrict__ W,
    const float* __restrict__ bias, const int* __restrict__ esrc,
    const int* __restrict__ edst, float* __restrict__ out, int N, int E)
{
    __shared__ short shb[BR * HSB];
    __shared__ int seg[BR + 1];

    const int t = threadIdx.x;
    const int base = blockIdx.x * BR;

    if (t < BR + 1) {
        int v = base + t;
        int lo = 0, hi = E;
        while (lo < hi) {
            int mid = (lo + hi) >> 1;
            if (edst[mid] < v) lo = mid + 1; else hi = mid;
        }
        seg[t] = lo;
    }
    __syncthreads();

    const int wave = t >> 6;
    const int lane = t & 63;
    const int sw = lane >> 5;
    const int sl = lane & 31;
    const int lb = sw << 5;
    const int rowbase = wave * 16;

    for (int it = 0; it < 8; ++it) {
        int cur_rb = rowbase + it * 2 + sw;
        int cur_r  = base + cur_rb;
        if (cur_r >= N) break;
        int cur_s = seg[cur_rb], cur_e = seg[cur_rb + 1];
        float4 a0 = make_float4(0.f, 0.f, 0.f, 0.f), a1 = a0;
        for (int cs = cur_s; cs < cur_e; cs += 32) {
            int m = cur_e - cs; if (m > 32) m = 32;
            int srcv = (cs + sl < cur_e) ? esrc[cs + sl] : 0;
            for (int j0 = 0; j0 < m; j0 += 8) {
                const int rem = m - j0;
#pragma unroll
                for (int u = 0; u < 8; ++u) {
                    int idx = __shfl(srcv, lb + ((j0 + u) & 31));
                    float4 v = *(const float4*)(x + (size_t)idx * FD + 4 * sl);
                    float f = (u < rem) ? 1.f : 0.f;
                    float4* A = (u & 1) ? &a1 : &a0;
                    A->x = fmaf(v.x, f, A->x);
                    A->y = fmaf(v.y, f, A->y);
                    A->z = fmaf(v.z, f, A->z);
                    A->w = fmaf(v.w, f, A->w);
                }
            }
        }
        float4 xvv = *(const float4*)(x + (size_t)cur_r * FD + 4 * sl);
        int deg = cur_e - cur_s;
        float inv = 1.0f / (float)(deg > 0 ? deg : 1);
        short4 hb;
        hb.x = f2bf(xvv.x + (a0.x + a1.x) * inv);
        hb.y = f2bf(xvv.y + (a0.y + a1.y) * inv);
        hb.z = f2bf(xvv.z + (a0.z + a1.z) * inv);
        hb.w = f2bf(xvv.w + (a0.w + a1.w) * inv);
        *(short4*)(shb + cur_rb * HSB + 4 * sl) = hb;
    }
    __syncthreads();

    const int lr = lane & 15;
    const int q  = lane >> 4;
    const int colb = wave * 32;

    bf16x8 bfr[2][4];
#pragma unroll
    for (int ct = 0; ct < 2; ++ct) {
        int col = colb + ct * 16 + lr;
#pragma unroll
        for (int kt = 0; kt < 4; ++kt) {
            bf16x8 f;
#pragma unroll
            for (int e = 0; e < 8; ++e)
                f[e] = f2bf(W[(size_t)(kt * 32 + q * 8 + e) * FD + col]);
            bfr[ct][kt] = f;
        }
    }

    f32x4 acc[4][2];
#pragma unroll
    for (int rt = 0; rt < 4; ++rt) {
        acc[rt][0] = (f32x4){0.f, 0.f, 0.f, 0.f};
        acc[rt][1] = (f32x4){0.f, 0.f, 0.f, 0.f};
    }

#pragma unroll
    for (int rt = 0; rt < 4; ++rt)
#pragma unroll
        for (int kt = 0; kt < 4; ++kt) {
            bf16x8 av = *(const bf16x8*)(shb + (rt * 16 + lr) * HSB + kt * 32 + q * 8);
            acc[rt][0] = __builtin_amdgcn_mfma_f32_16x16x32_bf16(av, bfr[0][kt], acc[rt][0], 0, 0, 0);
            acc[rt][1] = __builtin_amdgcn_mfma_f32_16x16x32_bf16(av, bfr[1][kt], acc[rt][1], 0, 0, 0);
        }

    const float b0 = bias[colb + lr];
    const float b1 = bias[colb + 16 + lr];

#pragma unroll
    for (int rt = 0; rt < 4; ++rt)
#pragma unroll
        for (int j = 0; j < 4; ++j) {
            int row = base + rt * 16 + q * 4 + j;
            if (row < N) {
                float v0 = acc[rt][0][j] + b0; v0 = v0 > 0.f ? v0 : 0.f;
                float v1 = acc[rt][1][j] + b1; v1 = v1 > 0.f ? v1 : 0.f;
                out[(size_t)row * FD + colb + lr]      = v0;
                out[(size_t)row * FD + colb + 16 + lr] = v1;
            }
        }
}

extern "C" void kernel_launch(void* const* d_in, const int* in_sizes, int n_in,
                              void* d_out, int out_size, void* d_ws, size_t ws_size,
                              hipStream_t stream) {
    const float* x    = (const float*)d_in[0];
    const float* W    = (const float*)d_in[1];
    const float* bias = (const float*)d_in[2];
    const int* esrc   = (const int*)d_in[3];
    const int* edst   = (const int*)d_in[4];
    float* out        = (float*)d_out;

    int N = in_sizes[0] / FD;
    int E = in_sizes[3];
    int blocks = (N + BR - 1) / BR;

    size_t rp_bytes = (size_t)(N + 1) * 4;
    size_t pk_off   = (rp_bytes + 511) & ~(size_t)511;
    size_t xb_off   = (pk_off + 2048 * 8 * 2 + 511) & ~(size_t)511;
    size_t need_med = pk_off + 2048 * 8 * 2;
    size_t need_big = xb_off + (size_t)N * FD * 2;

    if (ws_size >= need_big) {
        int* rp    = (int*)d_ws;
        short* pkW = (short*)((char*)d_ws + pk_off);
        short* xb  = (short*)((char*)d_ws + xb_off);
        prep_full_kernel<<<2048, 256, 0, stream>>>(x, W, edst, rp, pkW, xb, N, E);
        meanagg_main2_kernel<<<blocks, 256, 0, stream>>>(xb, pkW, bias, esrc, rp, out, N, E);
    } else if (ws_size >= need_med) {
        int* rp    = (int*)d_ws;
        short* pkW = (short*)((char*)d_ws + pk_off);
        int pblocks = (E + 255) / 256;
        prep_kernel<<<pblocks, 256, 0, stream>>>(W, edst, rp, pkW, N, E);
        meanagg_main_kernel<<<blocks, 256, 0, stream>>>(x, pkW, bias, esrc, rp, out, N, E);
    } else {
        meanagg_fused_kernel<<<blocks, 256, 0, stream>>>(x, W, bias, esrc, edst, out, N, E);
    }
}